// Round 4
// baseline (56.924 us; speedup 1.0000x reference)
//
#include <hip/hip_runtime.h>

#define BATCH 32
#define SS 1024
#define NSTEPS 972
#define LSTR 20                     // floats per lane row: 16 data + 4 pad = 80B (16B-aligned, 8-way bank spread)

#define UNVIS   0x7F000000u         // huge finite float sentinels (no NaN/Inf pitfalls in v_min_f32)
#define CLOSEDB 0x7F000001u
#define OBSTB   0x7F000002u

typedef unsigned long long ull;

template <int CTRL>
__device__ __forceinline__ int dpp32(int v) {
    return __builtin_amdgcn_update_dpp(v, v, CTRL, 0xF, 0xF, false);
}

// 64-lane f32 min, result (bit-exact copy of some input) broadcast from lane 63.
__device__ __forceinline__ float wave_min_f32_bcast(float v) {
    float t;
    t = __int_as_float(dpp32<0xB1 >(__float_as_int(v))); v = fminf(v, t);  // quad xor1
    t = __int_as_float(dpp32<0x4E >(__float_as_int(v))); v = fminf(v, t);  // quad xor2
    t = __int_as_float(dpp32<0x141>(__float_as_int(v))); v = fminf(v, t);  // row_half_mirror
    t = __int_as_float(dpp32<0x140>(__float_as_int(v))); v = fminf(v, t);  // row_mirror
    t = __int_as_float(dpp32<0x142>(__float_as_int(v))); v = fminf(v, t);  // row_bcast15
    t = __int_as_float(dpp32<0x143>(__float_as_int(v))); v = fminf(v, t);  // row_bcast31
    return __int_as_float(__builtin_amdgcn_readlane(__float_as_int(v), 63));
}

template <int CTRL>
__device__ __forceinline__ ull dpp64(ull k) {
    unsigned lo = (unsigned)dpp32<CTRL>((int)(unsigned)k);
    unsigned hi = (unsigned)dpp32<CTRL>((int)(unsigned)(k >> 32));
    return ((ull)hi << 32) | lo;
}

// u64 min within each 8-lane group (lanes 0-7 is the group we read).
__device__ __forceinline__ ull grp8_min_u64(ull k) {
    ull t;
    t = dpp64<0xB1 >(k); k = t < k ? t : k;
    t = dpp64<0x4E >(k); k = t < k ? t : k;
    t = dpp64<0x141>(k); k = t < k ? t : k;
    return k;
}

__device__ __forceinline__ unsigned candf(ull m, unsigned i) {
    // (first matching lane)*16 | slot  ==  flat cell index; 0xFFFFFFFF if no match
    return m ? ((((unsigned)__builtin_ctzll(m)) << 4) | i) : 0xFFFFFFFFu;
}
__device__ __forceinline__ unsigned umin2(unsigned a, unsigned b) { return a < b ? a : b; }

__global__ __launch_bounds__(64)
void astar_kernel(const float* __restrict__ start_maps,
                  const float* __restrict__ goal_maps,
                  const float* __restrict__ obst_maps,
                  float* __restrict__ out)
{
    const int b = blockIdx.x;
    const int lane = threadIdx.x;

    __shared__ __align__(16) float fop[64 * LSTR];   // padded: cell c at (c>>4)*LSTR + (c&15)
    __shared__ __align__(16) float g_s[SS];
    __shared__ __align__(16) float fh_s[SS];         // 0.501f * h
    __shared__ unsigned short par_s[SS];
    __shared__ int sh_start, sh_goal;

    const float* st = start_maps + b * SS;
    const float* gl = goal_maps + b * SS;
    const float* ob = obst_maps + b * SS;

    for (int i = 0; i < 16; ++i) {
        int c = i * 64 + lane;
        if (st[c] > 0.5f) sh_start = c;
        if (gl[c] > 0.5f) sh_goal = c;
    }
    __syncthreads();
    const int start_idx = sh_start;
    const int goal_idx = sh_goal;
    const float gi = (float)(goal_idx >> 5);
    const float gj = (float)(goal_idx & 31);
    const float SQRT2F = 1.41421356237309515f;   // fl32(sqrt(2))
    const float WH = 0.501f;

    for (int i = 0; i < 16; ++i) {
        int c = i * 64 + lane;
        float dx = fabsf((float)(c >> 5) - gi);
        float dy = fabsf((float)(c & 31) - gj);
        float h = __fadd_rn(__fmul_rn(fminf(dx, dy), SQRT2F), fabsf(dx - dy));
        fh_s[c] = __fmul_rn(WH, h);
        g_s[c] = 0.0f;
        par_s[c] = (unsigned short)goal_idx;
        fop[(c >> 4) * LSTR + (c & 15)] = __uint_as_float(ob[c] > 0.5f ? UNVIS : OBSTB);
    }
    __syncthreads();
    if (lane == 0)
        fop[(start_idx >> 4) * LSTR + (start_idx & 15)] = fh_s[start_idx];  // f = fl(0.5*0 + fh) = fh
    __syncthreads();

    const float* frow = &fop[lane * LSTR];
    float4 r0 = *(const float4*)(frow + 0);
    float4 r1 = *(const float4*)(frow + 4);
    float4 r2 = *(const float4*)(frow + 8);
    float4 r3 = *(const float4*)(frow + 12);
    unsigned nf_bits = 0xFFFFFFFFu;   // carried: min f-bits over cells relaxed last step
    unsigned n_idx = 0;               // and its flat index
    bool solved = false;

    for (int step = 0; step < NSTEPS; ++step) {
        // ---- stale-set value min (regs loaded before last step's relax writes) ----
        float m0 = fminf(fminf(r0.x, r0.y), fminf(r0.z, r0.w));
        float m1 = fminf(fminf(r1.x, r1.y), fminf(r1.z, r1.w));
        float m2 = fminf(fminf(r2.x, r2.y), fminf(r2.z, r2.w));
        float m3 = fminf(fminf(r3.x, r3.y), fminf(r3.z, r3.w));
        float gmin = wave_min_f32_bcast(fminf(fminf(m0, m1), fminf(m2, m3)));
        const unsigned gb = __float_as_uint(gmin);

        // ---- stale-set index (bit-exact match ballots; SALU ff1 + min tree) ----
        ull b0 = __ballot(__float_as_uint(r0.x) == gb), b1 = __ballot(__float_as_uint(r0.y) == gb);
        ull b2 = __ballot(__float_as_uint(r0.z) == gb), b3 = __ballot(__float_as_uint(r0.w) == gb);
        ull b4 = __ballot(__float_as_uint(r1.x) == gb), b5 = __ballot(__float_as_uint(r1.y) == gb);
        ull b6 = __ballot(__float_as_uint(r1.z) == gb), b7 = __ballot(__float_as_uint(r1.w) == gb);
        ull b8 = __ballot(__float_as_uint(r2.x) == gb), b9 = __ballot(__float_as_uint(r2.y) == gb);
        ull ba = __ballot(__float_as_uint(r2.z) == gb), bb = __ballot(__float_as_uint(r2.w) == gb);
        ull bc = __ballot(__float_as_uint(r3.x) == gb), bd = __ballot(__float_as_uint(r3.y) == gb);
        ull be = __ballot(__float_as_uint(r3.z) == gb), bf = __ballot(__float_as_uint(r3.w) == gb);
        unsigned c0 = umin2(candf(b0, 0),  candf(b1, 1));
        unsigned c1 = umin2(candf(b2, 2),  candf(b3, 3));
        unsigned c2 = umin2(candf(b4, 4),  candf(b5, 5));
        unsigned c3 = umin2(candf(b6, 6),  candf(b7, 7));
        unsigned c4 = umin2(candf(b8, 8),  candf(b9, 9));
        unsigned c5 = umin2(candf(ba, 10), candf(bb, 11));
        unsigned c6 = umin2(candf(bc, 12), candf(bd, 13));
        unsigned c7 = umin2(candf(be, 14), candf(bf, 15));
        unsigned best = umin2(umin2(umin2(c0, c1), umin2(c2, c3)),
                              umin2(umin2(c4, c5), umin2(c6, c7)));

        // ---- merge stale vs freshly-relaxed (strictly-decreased cells aren't stale-matchable) ----
        unsigned selu;
        if (nf_bits < gb)      selu = n_idx;
        else if (nf_bits > gb) selu = best;
        else                   selu = umin2(best, n_idx);
        const int sel = (int)selu;
        solved = (selu == (unsigned)goal_idx);
        const int si = sel >> 5, sj = sel & 31;

        // close sel, THEN issue next-step scan loads (in-order DS: loads see the close,
        // but not the relax writes below -> handled by the merge path next iteration)
        if (lane == 0)
            fop[(sel >> 4) * LSTR + (sel & 15)] = __uint_as_float(CLOSEDB);
        asm volatile("" ::: "memory");
        r0 = *(const float4*)(frow + 0);
        r1 = *(const float4*)(frow + 4);
        r2 = *(const float4*)(frow + 8);
        r3 = *(const float4*)(frow + 12);
        asm volatile("" ::: "memory");

        const float gsel = g_s[sel];           // uniform broadcast read
        // ---- 8-neighbor relax ----
        ull nk = ~0ull;
        if (lane < 8) {
            int k = lane < 4 ? lane : lane + 1;   // skip center
            int di = k / 3 - 1;
            int dj = k - (k / 3) * 3 - 1;
            int ni = si + di, nj = sj + dj;
            if ((unsigned)ni < 32u && (unsigned)nj < 32u) {
                int nb = ni * 32 + nj;
                int fa = (nb >> 4) * LSTR + (nb & 15);
                unsigned fbv = __float_as_uint(fop[fa]);
                float gnb = g_s[nb];
                float fh = fh_s[nb];
                float w = (di != 0 && dj != 0) ? SQRT2F : 1.0f;
                float g2 = __fadd_rn(gsel, w);
                // UNVIS -> open; CLOSED/OBST (> UNVIS) -> skip; open (< UNVIS) -> strict g improvement
                bool rel = (fbv == UNVIS) || (fbv < UNVIS && gnb > g2);
                if (rel) {
                    float fnew = __fadd_rn(__fmul_rn(0.5f, g2), fh);
                    fop[fa] = fnew;
                    g_s[nb] = g2;
                    par_s[nb] = (unsigned short)sel;
                    nk = (((ull)__float_as_uint(fnew)) << 10) | (unsigned)nb;
                }
            }
        }
        asm volatile("" ::: "memory");
        ull red = grp8_min_u64(nk);
        unsigned rlo = (unsigned)__builtin_amdgcn_readlane((int)(unsigned)red, 0);
        unsigned rhi = (unsigned)__builtin_amdgcn_readlane((int)(unsigned)(red >> 32), 0);
        nf_bits = (rhi << 22) | (rlo >> 10);
        n_idx = rlo & 1023u;

        if (solved) break;   // relax on the solved step already applied (matches reference)
    }

    float* out_hist = out + b * SS;
    float* out_path = out + BATCH * SS + b * SS;
    float* out_g    = out + 2 * BATCH * SS + b * SS;
    for (int i = 0; i < 16; ++i) {
        int c = i * 64 + lane;
        unsigned fbv = __float_as_uint(fop[(c >> 4) * LSTR + (c & 15)]);
        out_hist[c] = (fbv == CLOSEDB) ? 1.0f : 0.0f;
        out_g[c]    = g_s[c];
        out_path[c] = (c == goal_idx) ? 1.0f : 0.0f;
    }
    __syncthreads();   // drain stores before backtrack overwrites
    if (lane == 0) {
        int loc = par_s[goal_idx];
        for (int it = 0; it < NSTEPS; ++it) {
            out_path[loc] = 1.0f;
            if (loc == goal_idx) break;   // parent chain strictly decreasing in expansion time
            loc = par_s[loc];
        }
    }
}

extern "C" void kernel_launch(void* const* d_in, const int* in_sizes, int n_in,
                              void* d_out, int out_size, void* d_ws, size_t ws_size,
                              hipStream_t stream)
{
    // d_in: [0]=cost_maps (unused in 'default' mode), [1]=start, [2]=goal, [3]=obstacles
    const float* start_maps = (const float*)d_in[1];
    const float* goal_maps  = (const float*)d_in[2];
    const float* obst_maps  = (const float*)d_in[3];
    float* out = (float*)d_out;
    hipLaunchKernelGGL(astar_kernel, dim3(BATCH), dim3(64), 0, stream,
                       start_maps, goal_maps, obst_maps, out);
}

// Round 5
// 42.811 us; speedup vs baseline: 1.3297x; 1.3297x over previous
//
#include <hip/hip_runtime.h>

#define BATCH 32
#define SS 1024
#define NSTEPS 972
#define LSTR 20                     // floats per lane row: 16 data + 4 pad = 80B (16B-aligned, 8-way bank spread)

#define UNVIS   0x7F000000u         // huge finite float sentinels: UNVIS < CLOSED < OBST, all > any real f
#define CLOSEDB 0x7F000001u
#define OBSTB   0x7F000002u

typedef unsigned long long ull;

template <int CTRL>
__device__ __forceinline__ int dpp32(int v) {
    return __builtin_amdgcn_update_dpp(v, v, CTRL, 0xF, 0xF, false);
}

// 64-lane f32 min, result (bit-exact copy of some input) broadcast from lane 63.
__device__ __forceinline__ float wave_min_f32_bcast(float v) {
    float t;
    t = __int_as_float(dpp32<0xB1 >(__float_as_int(v))); v = fminf(v, t);  // quad xor1
    t = __int_as_float(dpp32<0x4E >(__float_as_int(v))); v = fminf(v, t);  // quad xor2
    t = __int_as_float(dpp32<0x141>(__float_as_int(v))); v = fminf(v, t);  // row_half_mirror
    t = __int_as_float(dpp32<0x140>(__float_as_int(v))); v = fminf(v, t);  // row_mirror
    t = __int_as_float(dpp32<0x142>(__float_as_int(v))); v = fminf(v, t);  // row_bcast15
    t = __int_as_float(dpp32<0x143>(__float_as_int(v))); v = fminf(v, t);  // row_bcast31
    return __int_as_float(__builtin_amdgcn_readlane(__float_as_int(v), 63));
}

__device__ __forceinline__ unsigned umin2(unsigned a, unsigned b) { return a < b ? a : b; }
__device__ __forceinline__ unsigned slotc(float v, unsigned lm, unsigned i) {
    return (__float_as_uint(v) == lm) ? i : 63u;   // lane-local slot candidate
}

__global__ __launch_bounds__(64)
void astar_kernel(const float* __restrict__ start_maps,
                  const float* __restrict__ goal_maps,
                  const float* __restrict__ obst_maps,
                  float* __restrict__ out)
{
    const int b = blockIdx.x;
    const int lane = threadIdx.x;

    __shared__ __align__(16) float fop[64 * LSTR];   // padded: cell c at (c>>4)*LSTR + (c&15)
    __shared__ __align__(16) float g_s[SS];
    __shared__ __align__(16) float fh_s[SS];         // 0.501f * h
    __shared__ unsigned short par_s[SS];
    __shared__ int sh_start, sh_goal;

    const float* st = start_maps + b * SS;
    const float* gl = goal_maps + b * SS;
    const float* ob = obst_maps + b * SS;

    for (int i = 0; i < 16; ++i) {
        int c = i * 64 + lane;
        if (st[c] > 0.5f) sh_start = c;
        if (gl[c] > 0.5f) sh_goal = c;
    }
    __syncthreads();
    const int start_idx = sh_start;
    const int goal_idx = sh_goal;
    const float gi = (float)(goal_idx >> 5);
    const float gj = (float)(goal_idx & 31);
    const float SQRT2F = 1.41421356237309515f;   // fl32(sqrt(2))
    const float WH = 0.501f;

    for (int i = 0; i < 16; ++i) {
        int c = i * 64 + lane;
        float dx = fabsf((float)(c >> 5) - gi);
        float dy = fabsf((float)(c & 31) - gj);
        float h = __fadd_rn(__fmul_rn(fminf(dx, dy), SQRT2F), fabsf(dx - dy));
        fh_s[c] = __fmul_rn(WH, h);
        g_s[c] = 0.0f;
        par_s[c] = (unsigned short)goal_idx;
        fop[(c >> 4) * LSTR + (c & 15)] = __uint_as_float(ob[c] > 0.5f ? UNVIS : OBSTB);
    }
    __syncthreads();
    if (lane == 0)
        fop[(start_idx >> 4) * LSTR + (start_idx & 15)] = fh_s[start_idx];  // f = fl(0.5*0 + fh) = fh
    __syncthreads();

    const float* frow = &fop[lane * LSTR];
    float4 r0 = *(const float4*)(frow + 0);
    float4 r1 = *(const float4*)(frow + 4);
    float4 r2 = *(const float4*)(frow + 8);
    float4 r3 = *(const float4*)(frow + 12);
    bool solved = false;

    #pragma unroll 1
    for (int step = 0; step < NSTEPS; ++step) {
        // ---- local value min over this lane's 16 cells (v_min3-friendly tree) ----
        float a0 = fminf(fminf(r0.x, r0.y), fminf(r0.z, r0.w));
        float a1 = fminf(fminf(r1.x, r1.y), fminf(r1.z, r1.w));
        float a2 = fminf(fminf(r2.x, r2.y), fminf(r2.z, r2.w));
        float a3 = fminf(fminf(r3.x, r3.y), fminf(r3.z, r3.w));
        float lmin = fminf(fminf(a0, a1), fminf(a2, a3));
        const unsigned lm = __float_as_uint(lmin);

        // ---- local slot (lowest i with bits==lm); independent of the DPP chain -> overlaps ----
        unsigned s0 = umin2(umin2(slotc(r0.x, lm, 0),  slotc(r0.y, lm, 1)),
                            umin2(slotc(r0.z, lm, 2),  slotc(r0.w, lm, 3)));
        unsigned s1 = umin2(umin2(slotc(r1.x, lm, 4),  slotc(r1.y, lm, 5)),
                            umin2(slotc(r1.z, lm, 6),  slotc(r1.w, lm, 7)));
        unsigned s2 = umin2(umin2(slotc(r2.x, lm, 8),  slotc(r2.y, lm, 9)),
                            umin2(slotc(r2.z, lm, 10), slotc(r2.w, lm, 11)));
        unsigned s3 = umin2(umin2(slotc(r3.x, lm, 12), slotc(r3.y, lm, 13)),
                            umin2(slotc(r3.z, lm, 14), slotc(r3.w, lm, 15)));
        unsigned slot = umin2(umin2(s0, s1), umin2(s2, s3));

        // ---- wave min + owner (lowest lane among ties == lowest cell block) ----
        const float gmin = wave_min_f32_bcast(lmin);
        const ull bal = __ballot(lm == __float_as_uint(gmin));
        const int owner = (int)__builtin_ctzll(bal);
        const int sel = owner * 16 + __builtin_amdgcn_readlane((int)slot, owner);
        solved = (sel == goal_idx);
        const int si = sel >> 5, sj = sel & 31;

        // close sel (distinct address from all neighbor reads below)
        if (lane == 0)
            fop[(sel >> 4) * LSTR + (sel & 15)] = __uint_as_float(CLOSEDB);
        asm volatile("" ::: "memory");

        // gsel: uniform LDS broadcast read, batched with the relax reads -> one lgkm wait
        const float gsel = g_s[sel];

        // ---- 8-neighbor relax ----
        if (lane < 8) {
            int k = lane < 4 ? lane : lane + 1;   // skip center
            int di = k / 3 - 1;
            int dj = k - (k / 3) * 3 - 1;
            int ni = si + di, nj = sj + dj;
            if ((unsigned)ni < 32u && (unsigned)nj < 32u) {
                int nb = ni * 32 + nj;
                int fa = (nb >> 4) * LSTR + (nb & 15);
                unsigned fbv = __float_as_uint(fop[fa]);
                float gnb = g_s[nb];
                float fh = fh_s[nb];
                float w = (di != 0 && dj != 0) ? SQRT2F : 1.0f;
                float g2 = __fadd_rn(gsel, w);
                // UNVIS -> open; CLOSED/OBST (> UNVIS) -> skip; open (< UNVIS) -> strict g improvement
                bool rel = (fbv == UNVIS) || (fbv < UNVIS && gnb > g2);
                if (rel) {
                    fop[fa] = __fadd_rn(__fmul_rn(0.5f, g2), fh);
                    g_s[nb] = g2;
                    par_s[nb] = (unsigned short)sel;
                }
            }
        }
        asm volatile("" ::: "memory");
        // next-step scan loads: issued AFTER relax writes (in-order DS -> they see the
        // close + all relaxes); latency partially hidden by loop-back + value tree wait
        r0 = *(const float4*)(frow + 0);
        r1 = *(const float4*)(frow + 4);
        r2 = *(const float4*)(frow + 8);
        r3 = *(const float4*)(frow + 12);
        asm volatile("" ::: "memory");

        if (solved) break;   // exact: state provably constant after goal selection
    }

    float* out_hist = out + b * SS;
    float* out_path = out + BATCH * SS + b * SS;
    float* out_g    = out + 2 * BATCH * SS + b * SS;
    for (int i = 0; i < 16; ++i) {
        int c = i * 64 + lane;
        unsigned fbv = __float_as_uint(fop[(c >> 4) * LSTR + (c & 15)]);
        out_hist[c] = (fbv == CLOSEDB) ? 1.0f : 0.0f;
        out_g[c]    = g_s[c];
        out_path[c] = (c == goal_idx) ? 1.0f : 0.0f;
    }
    __syncthreads();   // drain stores before backtrack overwrites
    if (lane == 0) {
        int loc = par_s[goal_idx];
        for (int it = 0; it < NSTEPS; ++it) {
            out_path[loc] = 1.0f;
            if (loc == goal_idx) break;   // parent chain strictly decreasing in expansion time
            loc = par_s[loc];
        }
    }
}

extern "C" void kernel_launch(void* const* d_in, const int* in_sizes, int n_in,
                              void* d_out, int out_size, void* d_ws, size_t ws_size,
                              hipStream_t stream)
{
    // d_in: [0]=cost_maps (unused in 'default' mode), [1]=start, [2]=goal, [3]=obstacles
    const float* start_maps = (const float*)d_in[1];
    const float* goal_maps  = (const float*)d_in[2];
    const float* obst_maps  = (const float*)d_in[3];
    float* out = (float*)d_out;
    hipLaunchKernelGGL(astar_kernel, dim3(BATCH), dim3(64), 0, stream,
                       start_maps, goal_maps, obst_maps, out);
}

// Round 6
// 42.729 us; speedup vs baseline: 1.3322x; 1.0019x over previous
//
#include <hip/hip_runtime.h>

#define BATCH 32
#define SS 1024
#define NSTEPS 972
#define LSTR 20                     // floats per lane row: 16 data + 4 pad = 80B (16B-aligned, 8-way bank spread)

#define UNVIS   0x7F000000u         // huge finite float sentinels: UNVIS < CLOSED < OBST, all > any real f
#define CLOSEDB 0x7F000001u
#define OBSTB   0x7F000002u

typedef unsigned long long ull;

template <int CTRL>
__device__ __forceinline__ int dpp32(int v) {
    return __builtin_amdgcn_update_dpp(v, v, CTRL, 0xF, 0xF, false);
}

// 64-lane f32 min, result (bit-exact copy of some input) broadcast from lane 63.
__device__ __forceinline__ float wave_min_f32_bcast(float v) {
    float t;
    t = __int_as_float(dpp32<0xB1 >(__float_as_int(v))); v = fminf(v, t);  // quad xor1
    t = __int_as_float(dpp32<0x4E >(__float_as_int(v))); v = fminf(v, t);  // quad xor2
    t = __int_as_float(dpp32<0x141>(__float_as_int(v))); v = fminf(v, t);  // row_half_mirror
    t = __int_as_float(dpp32<0x140>(__float_as_int(v))); v = fminf(v, t);  // row_mirror
    t = __int_as_float(dpp32<0x142>(__float_as_int(v))); v = fminf(v, t);  // row_bcast15
    t = __int_as_float(dpp32<0x143>(__float_as_int(v))); v = fminf(v, t);  // row_bcast31
    return __int_as_float(__builtin_amdgcn_readlane(__float_as_int(v), 63));
}

__device__ __forceinline__ unsigned umin2(unsigned a, unsigned b) { return a < b ? a : b; }
__device__ __forceinline__ unsigned slotc(float v, unsigned lm, unsigned i) {
    return (__float_as_uint(v) == lm) ? i : 63u;   // lane-local slot candidate
}

__global__ __launch_bounds__(64)
void astar_kernel(const float* __restrict__ start_maps,
                  const float* __restrict__ goal_maps,
                  const float* __restrict__ obst_maps,
                  float* __restrict__ out)
{
    const int b = blockIdx.x;
    const int lane = threadIdx.x;

    __shared__ __align__(16) float fop[64 * LSTR];   // padded: cell c at (c>>4)*LSTR + (c&15)
    __shared__ __align__(16) float g_s[SS];
    __shared__ __align__(16) float fh_s[SS];         // 0.501f * h
    __shared__ unsigned short par_s[SS];
    __shared__ int sh_start, sh_goal;

    const float* st = start_maps + b * SS;
    const float* gl = goal_maps + b * SS;
    const float* ob = obst_maps + b * SS;

    for (int i = 0; i < 16; ++i) {
        int c = i * 64 + lane;
        if (st[c] > 0.5f) sh_start = c;
        if (gl[c] > 0.5f) sh_goal = c;
    }
    __syncthreads();
    const int start_idx = sh_start;
    const int goal_idx = sh_goal;
    const float gi = (float)(goal_idx >> 5);
    const float gj = (float)(goal_idx & 31);
    const float SQRT2F = 1.41421356237309515f;   // fl32(sqrt(2))
    const float WH = 0.501f;

    for (int i = 0; i < 16; ++i) {
        int c = i * 64 + lane;
        float dx = fabsf((float)(c >> 5) - gi);
        float dy = fabsf((float)(c & 31) - gj);
        float h = __fadd_rn(__fmul_rn(fminf(dx, dy), SQRT2F), fabsf(dx - dy));
        fh_s[c] = __fmul_rn(WH, h);
        g_s[c] = 0.0f;
        par_s[c] = (unsigned short)goal_idx;
        fop[(c >> 4) * LSTR + (c & 15)] = __uint_as_float(ob[c] > 0.5f ? UNVIS : OBSTB);
    }
    __syncthreads();
    if (lane == 0)
        fop[(start_idx >> 4) * LSTR + (start_idx & 15)] = fh_s[start_idx];  // f = fl(0.5*0 + fh) = fh
    __syncthreads();

    const float* frow = &fop[lane * LSTR];
    float4 r0 = *(const float4*)(frow + 0);
    float4 r1 = *(const float4*)(frow + 4);
    float4 r2 = *(const float4*)(frow + 8);
    float4 r3 = *(const float4*)(frow + 12);
    bool solved = false;

    #pragma unroll 1
    for (int step = 0; step < NSTEPS; ++step) {
        // ---- local value min over this lane's 16 cells (v_min3-friendly tree) ----
        float a0 = fminf(fminf(r0.x, r0.y), fminf(r0.z, r0.w));
        float a1 = fminf(fminf(r1.x, r1.y), fminf(r1.z, r1.w));
        float a2 = fminf(fminf(r2.x, r2.y), fminf(r2.z, r2.w));
        float a3 = fminf(fminf(r3.x, r3.y), fminf(r3.z, r3.w));
        float lmin = fminf(fminf(a0, a1), fminf(a2, a3));
        const unsigned lm = __float_as_uint(lmin);

        // ---- local slot (lowest i with bits==lm); independent of the DPP chain -> overlaps ----
        unsigned s0 = umin2(umin2(slotc(r0.x, lm, 0),  slotc(r0.y, lm, 1)),
                            umin2(slotc(r0.z, lm, 2),  slotc(r0.w, lm, 3)));
        unsigned s1 = umin2(umin2(slotc(r1.x, lm, 4),  slotc(r1.y, lm, 5)),
                            umin2(slotc(r1.z, lm, 6),  slotc(r1.w, lm, 7)));
        unsigned s2 = umin2(umin2(slotc(r2.x, lm, 8),  slotc(r2.y, lm, 9)),
                            umin2(slotc(r2.z, lm, 10), slotc(r2.w, lm, 11)));
        unsigned s3 = umin2(umin2(slotc(r3.x, lm, 12), slotc(r3.y, lm, 13)),
                            umin2(slotc(r3.z, lm, 14), slotc(r3.w, lm, 15)));
        unsigned slot = umin2(umin2(s0, s1), umin2(s2, s3));

        // ---- wave min + owner (lowest lane among ties == lowest cell block) ----
        const float gmin = wave_min_f32_bcast(lmin);
        const ull bal = __ballot(lm == __float_as_uint(gmin));
        const int owner = (int)__builtin_ctzll(bal);
        const int sel = owner * 16 + __builtin_amdgcn_readlane((int)slot, owner);
        solved = (sel == goal_idx);
        const int si = sel >> 5, sj = sel & 31;

        // close sel (distinct address from all neighbor reads below)
        if (lane == 0)
            fop[(sel >> 4) * LSTR + (sel & 15)] = __uint_as_float(CLOSEDB);
        asm volatile("" ::: "memory");

        // gsel: uniform LDS broadcast read, batched with the relax reads -> one lgkm wait
        const float gsel = g_s[sel];

        // ---- 8-neighbor relax ----
        if (lane < 8) {
            int k = lane < 4 ? lane : lane + 1;   // skip center
            int di = k / 3 - 1;
            int dj = k - (k / 3) * 3 - 1;
            int ni = si + di, nj = sj + dj;
            if ((unsigned)ni < 32u && (unsigned)nj < 32u) {
                int nb = ni * 32 + nj;
                int fa = (nb >> 4) * LSTR + (nb & 15);
                unsigned fbv = __float_as_uint(fop[fa]);
                float gnb = g_s[nb];
                float fh = fh_s[nb];
                float w = (di != 0 && dj != 0) ? SQRT2F : 1.0f;
                float g2 = __fadd_rn(gsel, w);
                // UNVIS -> open; CLOSED/OBST (> UNVIS) -> skip; open (< UNVIS) -> strict g improvement
                bool rel = (fbv == UNVIS) || (fbv < UNVIS && gnb > g2);
                if (rel) {
                    fop[fa] = __fadd_rn(__fmul_rn(0.5f, g2), fh);
                    g_s[nb] = g2;
                    par_s[nb] = (unsigned short)sel;
                }
            }
        }
        asm volatile("" ::: "memory");
        // next-step scan loads: issued AFTER relax writes (in-order DS -> they see the
        // close + all relaxes); latency partially hidden by loop-back + value tree wait
        r0 = *(const float4*)(frow + 0);
        r1 = *(const float4*)(frow + 4);
        r2 = *(const float4*)(frow + 8);
        r3 = *(const float4*)(frow + 12);
        asm volatile("" ::: "memory");

        if (solved) break;   // exact: state provably constant after goal selection
    }

    float* out_hist = out + b * SS;
    float* out_path = out + BATCH * SS + b * SS;
    float* out_g    = out + 2 * BATCH * SS + b * SS;
    for (int i = 0; i < 16; ++i) {
        int c = i * 64 + lane;
        unsigned fbv = __float_as_uint(fop[(c >> 4) * LSTR + (c & 15)]);
        out_hist[c] = (fbv == CLOSEDB) ? 1.0f : 0.0f;
        out_g[c]    = g_s[c];
        out_path[c] = (c == goal_idx) ? 1.0f : 0.0f;
    }
    __syncthreads();   // drain stores before backtrack overwrites
    if (lane == 0) {
        int loc = par_s[goal_idx];
        for (int it = 0; it < NSTEPS; ++it) {
            out_path[loc] = 1.0f;
            if (loc == goal_idx) break;   // parent chain strictly decreasing in expansion time
            loc = par_s[loc];
        }
    }
}

extern "C" void kernel_launch(void* const* d_in, const int* in_sizes, int n_in,
                              void* d_out, int out_size, void* d_ws, size_t ws_size,
                              hipStream_t stream)
{
    // d_in: [0]=cost_maps (unused in 'default' mode), [1]=start, [2]=goal, [3]=obstacles
    const float* start_maps = (const float*)d_in[1];
    const float* goal_maps  = (const float*)d_in[2];
    const float* obst_maps  = (const float*)d_in[3];
    float* out = (float*)d_out;
    hipLaunchKernelGGL(astar_kernel, dim3(BATCH), dim3(64), 0, stream,
                       start_maps, goal_maps, obst_maps, out);
}